// Round 10
// baseline (435.051 us; speedup 1.0000x reference)
//
#include <hip/hip_runtime.h>
#include <stdint.h>

#define NN 20000
#define NNP 20096   // padded to multiple of 128 rows
#define NE 320000
#define NG 64

typedef unsigned short u16;
typedef __attribute__((ext_vector_type(8))) short short8;
typedef __attribute__((ext_vector_type(4))) float f32x4;

__device__ __forceinline__ void glds16(const void* g, const void* l) {
    __builtin_amdgcn_global_load_lds((const __attribute__((address_space(1))) void*)g,
                                     (__attribute__((address_space(3))) void*)l, 16, 0, 0);
}

__device__ __forceinline__ u16 f2bf(float f) {
    unsigned u = __float_as_uint(f);
    return (u16)((u + 0x7FFFu + ((u >> 16) & 1u)) >> 16);
}

// ---------------- CSR build ----------------
__global__ void hist_kernel(const int* __restrict__ dst, int* __restrict__ cnt, int E) {
    int i = blockIdx.x * blockDim.x + threadIdx.x;
    if (i < E) atomicAdd(&cnt[dst[i]], 1);
}

__global__ void scan_kernel(const int* __restrict__ cnt, int* __restrict__ rp, int n) {
    __shared__ int part[1024];
    int tid = threadIdx.x;
    const int CH = (n + 1023) / 1024;
    int base = tid * CH;
    int s = 0;
    for (int i = 0; i < CH; i++) { int idx = base + i; if (idx < n) s += cnt[idx]; }
    part[tid] = s;
    __syncthreads();
    for (int off = 1; off < 1024; off <<= 1) {
        int v = (tid >= off) ? part[tid - off] : 0;
        __syncthreads();
        part[tid] += v;
        __syncthreads();
    }
    int run = (tid == 0) ? 0 : part[tid - 1];
    for (int i = 0; i < CH; i++) {
        int idx = base + i;
        if (idx < n) { rp[idx] = run; run += cnt[idx]; }
    }
    if (tid == 1023) rp[n] = part[1023];
}

__global__ void copy_int(const int* __restrict__ a, int* __restrict__ b, int n) {
    int i = blockIdx.x * blockDim.x + threadIdx.x;
    if (i < n) b[i] = a[i];
}

__global__ void scatter_kernel(const int* __restrict__ src, const int* __restrict__ dstv,
                               int* __restrict__ ofs, int* __restrict__ col, int E) {
    int i = blockIdx.x * blockDim.x + threadIdx.x;
    if (i < E) {
        int p = atomicAdd(&ofs[dstv[i]], 1);
        col[p] = src[i];
    }
}

// ---------------- degree-bucketed node order (kills wave divergence in props) ----------------
__global__ void deg_hist(const int* __restrict__ rp, int* __restrict__ dh) {
    int i = blockIdx.x * blockDim.x + threadIdx.x;
    if (i < NN) { int d = rp[i + 1] - rp[i]; if (d > 63) d = 63; atomicAdd(&dh[d], 1); }
}

__global__ void deg_scan(const int* __restrict__ dh, int* __restrict__ doff) {
    if (threadIdx.x == 0) {
        int acc = 0;
        for (int i = 0; i < 64; i++) { doff[i] = acc; acc += dh[i]; }
    }
}

__global__ void deg_scatter(const int* __restrict__ rp, int* __restrict__ doff,
                            int* __restrict__ order) {
    int i = blockIdx.x * blockDim.x + threadIdx.x;
    if (i < NN) {
        int d = rp[i + 1] - rp[i]; if (d > 63) d = 63;
        int p = atomicAdd(&doff[d], 1);
        order[p] = i;
    }
}

// ---------------- convert x -> bf16 into S1 block 0 ----------------
__global__ void conv_x(const float* __restrict__ x, u16* __restrict__ S1) {
    int i = blockIdx.x * blockDim.x + threadIdx.x;   // one per 8 elements
    if (i >= NN * 128 / 8) return;
    int row = i >> 4, c = (i & 15) * 8;
    const float* p = x + (size_t)row * 128 + c;
    uint4 r;
    unsigned* pr = (unsigned*)&r;
#pragma unroll
    for (int j = 0; j < 4; j++)
        pr[j] = (unsigned)f2bf(p[2 * j]) | ((unsigned)f2bf(p[2 * j + 1]) << 16);
    *(uint4*)(S1 + (size_t)row * 512 + c) = r;
}

// ---------------- LDS-tiled transpose+convert: WT[m][k] = bf16(W[k][m]), K,M mult of 32 ----------------
__global__ void convT(const float* __restrict__ W, u16* __restrict__ WT, int K, int M) {
    __shared__ float tile[32][33];
    int m0 = blockIdx.x * 32, k0 = blockIdx.y * 32;
    int tx = threadIdx.x & 31, ty = threadIdx.x >> 5;   // 256 threads: 8 rows/pass
#pragma unroll
    for (int i = 0; i < 32; i += 8)
        tile[ty + i][tx] = W[(size_t)(k0 + ty + i) * M + m0 + tx];
    __syncthreads();
#pragma unroll
    for (int i = 0; i < 32; i += 8)
        WT[(size_t)(m0 + ty + i) * K + k0 + tx] = f2bf(tile[tx][ty + i]);
}

// ---------------- decode pooled genc -> bf16 matrix ----------------
__global__ void g2bf(const unsigned* __restrict__ genc, u16* __restrict__ gb) {
    int i = blockIdx.x * blockDim.x + threadIdx.x;
    if (i >= NG * 512) return;
    unsigned u = genc[i];
    u = (u & 0x80000000u) ? (u ^ 0x80000000u) : ~u;
    gb[i] = f2bf(__uint_as_float(u));
}

// ---------------- propagation (bf16), unroll-4 ILP, degree-ordered nodes ----------------
template <int NCHUNK>
__global__ __launch_bounds__(256) void prop_bf16(
    const int* __restrict__ rp, const int* __restrict__ col, const int* __restrict__ order,
    u16* __restrict__ S, int stride, int in_off, int out_off) {
    constexpr int NPB = 256 / NCHUNK;
    int idx = blockIdx.x * NPB + (threadIdx.x / NCHUNK);
    int c = threadIdx.x & (NCHUNK - 1);
    if (idx >= NN) return;
    int node = order[idx];
    int s0 = rp[node], s1 = rp[node + 1];
    float acc[8] = {};
    const u16* base = S + in_off + c * 8;
    auto accum = [&](uint4 v) {
        const unsigned* pv = (const unsigned*)&v;
#pragma unroll
        for (int j = 0; j < 4; j++) {
            acc[2 * j]     += __uint_as_float(pv[j] << 16);
            acc[2 * j + 1] += __uint_as_float(pv[j] & 0xFFFF0000u);
        }
    };
    int e = s0;
    for (; e + 4 <= s1; e += 4) {
        int i0 = col[e], i1 = col[e + 1], i2 = col[e + 2], i3 = col[e + 3];
        uint4 v0 = *(const uint4*)(base + (size_t)i0 * stride);
        uint4 v1 = *(const uint4*)(base + (size_t)i1 * stride);
        uint4 v2 = *(const uint4*)(base + (size_t)i2 * stride);
        uint4 v3 = *(const uint4*)(base + (size_t)i3 * stride);
        accum(v0); accum(v1); accum(v2); accum(v3);
    }
    for (; e < s1; e++)
        accum(*(const uint4*)(base + (size_t)col[e] * stride));
    uint4 r;
    unsigned* pr = (unsigned*)&r;
#pragma unroll
    for (int j = 0; j < 4; j++)
        pr[j] = (unsigned)f2bf(acc[2 * j]) | ((unsigned)f2bf(acc[2 * j + 1]) << 16);
    *(uint4*)(S + (size_t)node * stride + out_off + c * 8) = r;
}

// ---------------- bf16 MFMA GEMM, TMx128 tile, BK=32, 4 waves ----------------
// Double-buffered stage-early K-loop; bijective XCD-chunked swizzle.
// A: [*][lda] bf16 row-major. BT: [M][Kp] bf16 row-major (pre-transposed W).
// EPI 0: out = bf16(act(acc+bias)), ACT 0=leaky 1=relu. EPI 1 (TM=128): LDS-staged max pool.
template <int TM, int EPI, int ACT>
__global__ __launch_bounds__(256) void gemm_bf16(
    const u16* __restrict__ A, int lda, const u16* __restrict__ BT,
    int Kp, int M, const float* __restrict__ bias,
    u16* __restrict__ outB, int ldo,
    unsigned* __restrict__ genc, const int* __restrict__ batch) {
    __shared__ u16 Al[2][TM * 32];
    __shared__ u16 Bl[2][128 * 32];
    __shared__ unsigned gbuf[EPI == 1 ? 256 : 4];
    constexpr int MR = TM / 32;   // m-fragments per wave
    int gx = gridDim.x;
    int total = gx * gridDim.y;
    int flat = blockIdx.x + gx * blockIdx.y;
    int q = total >> 3, r_ = total & 7;
    int k8 = flat & 7, i8 = flat >> 3;
    int v = (k8 < r_) ? (k8 * (q + 1) + i8) : (r_ * (q + 1) + (k8 - r_) * q + i8);
    int col0 = (v % gx) * 128, row0 = (v / gx) * TM;
    int t = threadIdx.x;
    int w = t >> 6, ln = t & 63;
    int wm = (w >> 1) * (TM / 2), wn = (w & 1) * 64;
    int srowB = w * 32 + (ln >> 2);
    int srowA = (TM == 128) ? srowB : (w * 16 + (ln >> 2));
    int skc = (ln & 3) * 8;
    f32x4 acc[MR][4] = {};

    if (EPI == 1) gbuf[t] = 0;     // published by first loop barrier

    auto stage = [&](int b, int k0) {
        if constexpr (TM == 128) {
            glds16(A + (size_t)(row0 + srowA) * lda + k0 + skc,      &Al[b][w * 1024]);
            glds16(A + (size_t)(row0 + srowA + 16) * lda + k0 + skc, &Al[b][w * 1024 + 512]);
        } else {
            glds16(A + (size_t)(row0 + srowA) * lda + k0 + skc,      &Al[b][w * 512]);
        }
        glds16(BT + (size_t)(col0 + srowB) * Kp + k0 + skc,          &Bl[b][w * 1024]);
        glds16(BT + (size_t)(col0 + srowB + 16) * Kp + k0 + skc,     &Bl[b][w * 1024 + 512]);
    };

    int nt = Kp / 32;
    stage(0, 0);
    for (int it = 0; it < nt; it++) {
        int cur = it & 1;
        __syncthreads();                 // implicit vmcnt(0): buf[cur] ready & visible
        if (it + 1 < nt) stage(cur ^ 1, (it + 1) * 32);   // async fill other buffer
        short8 af[MR], bf[4];
#pragma unroll
        for (int m = 0; m < MR; m++)
            af[m] = *(const short8*)&Al[cur][(wm + m * 16 + (ln & 15)) * 32 + (ln >> 4) * 8];
#pragma unroll
        for (int n = 0; n < 4; n++)
            bf[n] = *(const short8*)&Bl[cur][(wn + n * 16 + (ln & 15)) * 32 + (ln >> 4) * 8];
#pragma unroll
        for (int m = 0; m < MR; m++)
#pragma unroll
            for (int n = 0; n < 4; n++)
                acc[m][n] = __builtin_amdgcn_mfma_f32_16x16x32_bf16(af[m], bf[n], acc[m][n], 0, 0, 0);
    }

    int g_lo = (EPI == 1) ? batch[row0] : 0;
#pragma unroll
    for (int m = 0; m < MR; m++) {
#pragma unroll
        for (int r = 0; r < 4; r++) {
            int row = row0 + wm + m * 16 + (ln >> 4) * 4 + r;
            if (row < NN) {
                int gb_ = 0, gidx = 0;
                if (EPI == 1) { gb_ = batch[row]; gidx = gb_ - g_lo; }
#pragma unroll
                for (int n = 0; n < 4; n++) {
                    int cl = wn + n * 16 + (ln & 15);
                    float vv = acc[m][n][r] + bias[col0 + cl];
                    if (EPI == 0) {
                        vv = ACT ? fmaxf(vv, 0.f) : (vv > 0.f ? vv : 0.01f * vv);
                        outB[(size_t)row * ldo + col0 + cl] = f2bf(vv);
                    } else {
                        unsigned u = __float_as_uint(vv);
                        u = (u & 0x80000000u) ? ~u : (u | 0x80000000u);
                        if (gidx < 2) atomicMax(&gbuf[gidx * 128 + cl], u);
                        else          atomicMax(&genc[(size_t)gb_ * M + col0 + cl], u);
                    }
                }
            }
        }
    }
    if (EPI == 1) {
        __syncthreads();
        int j = t >> 7, c = t & 127;
        unsigned u = gbuf[j * 128 + c];
        if (u && g_lo + j < NG) atomicMax(&genc[(size_t)(g_lo + j) * M + col0 + c], u);
    }
}

// ---------------- final head layer: out[r][m] = dot(m2b[r], Wm3[:,m]) + b[m] ----------------
__global__ void head3(const u16* __restrict__ m2b, const float* __restrict__ W,
                      const float* __restrict__ b, float* __restrict__ outp) {
    int r = blockIdx.x;           // 64 blocks
    int w = threadIdx.x >> 6;     // wave = output column (4)
    int ln = threadIdx.x & 63;
    float acc = 0.f;
    for (int k = ln; k < 512; k += 64) {
        float v = __uint_as_float(((unsigned)m2b[r * 512 + k]) << 16);
        acc += v * W[k * 4 + w];
    }
#pragma unroll
    for (int o = 32; o; o >>= 1) acc += __shfl_down(acc, o, 64);
    if (ln == 0) outp[r * 4 + w] = acc + b[w];
}

extern "C" void kernel_launch(void* const* d_in, const int* in_sizes, int n_in,
                              void* d_out, int out_size, void* d_ws, size_t ws_size,
                              hipStream_t stream) {
    const float* x   = (const float*)d_in[0];
    const int*   ei  = (const int*)d_in[1];
    const int*   bat = (const int*)d_in[2];
    const float* W1  = (const float*)d_in[3];
    const float* b1  = (const float*)d_in[4];
    const float* W2  = (const float*)d_in[5];
    const float* b2  = (const float*)d_in[6];
    const float* W3  = (const float*)d_in[7];
    const float* b3  = (const float*)d_in[8];
    const float* Wm1 = (const float*)d_in[9];
    const float* bm1 = (const float*)d_in[10];
    const float* Wm2 = (const float*)d_in[11];
    const float* bm2 = (const float*)d_in[12];
    const float* Wm3 = (const float*)d_in[13];
    const float* bm3 = (const float*)d_in[14];
    float* out = (float*)d_out;

    char* ws = (char*)d_ws;
    size_t off = 0;
    auto alloc = [&](size_t bytes) -> void* {
        void* p = ws + off;
        off += (bytes + 255) & ~(size_t)255;
        return p;
    };
    int*      cnt  = (int*)alloc((size_t)NN * 4);
    int*      rp   = (int*)alloc((size_t)(NN + 1) * 4);
    int*      col  = (int*)alloc((size_t)NE * 4);
    int*      order= (int*)alloc((size_t)NN * 4);
    int*      dh   = (int*)alloc(64 * 4);
    int*      doff = (int*)alloc(64 * 4);
    u16*      S1   = (u16*)alloc((size_t)NNP * 512 * 2);   // [x|Ax|A2x|A3x]
    u16*      S2   = (u16*)alloc((size_t)NNP * 512 * 2);   // [h1|Ah1|A2h1|A3h1]
    u16*      S3   = (u16*)alloc((size_t)NNP * 1024 * 2);  // [h2|Ah2|A2h2|A3h2]
    u16*      WT1  = (u16*)alloc((size_t)128 * 512 * 2);
    u16*      WT2  = (u16*)alloc((size_t)256 * 512 * 2);
    u16*      WT3  = (u16*)alloc((size_t)512 * 1024 * 2);
    u16*      WTm1 = (u16*)alloc((size_t)1024 * 512 * 2);
    u16*      WTm2 = (u16*)alloc((size_t)512 * 1024 * 2);
    unsigned* genc = (unsigned*)alloc((size_t)NG * 512 * 4);
    u16*      gb   = (u16*)alloc((size_t)NG * 512 * 2);
    u16*      m1b  = (u16*)alloc((size_t)NG * 1024 * 2);
    u16*      m2b  = (u16*)alloc((size_t)NG * 512 * 2);

    const int* src  = ei;
    const int* dstv = ei + NE;

    // CSR by destination
    hipMemsetAsync(cnt, 0, (size_t)NN * 4, stream);
    hist_kernel<<<(NE + 255) / 256, 256, 0, stream>>>(dstv, cnt, NE);
    scan_kernel<<<1, 1024, 0, stream>>>(cnt, rp, NN);
    copy_int<<<(NN + 255) / 256, 256, 0, stream>>>(rp, cnt, NN);
    scatter_kernel<<<(NE + 255) / 256, 256, 0, stream>>>(src, dstv, cnt, col, NE);

    // degree-bucketed node order
    hipMemsetAsync(dh, 0, 64 * 4, stream);
    deg_hist<<<(NN + 255) / 256, 256, 0, stream>>>(rp, dh);
    deg_scan<<<1, 64, 0, stream>>>(dh, doff);
    deg_scatter<<<(NN + 255) / 256, 256, 0, stream>>>(rp, doff, order);

    // weights -> bf16, transposed [M][K] (K,M all multiples of 32)
    convT<<<dim3(128 / 32, 512 / 32), 256, 0, stream>>>(W1, WT1, 512, 128);
    convT<<<dim3(256 / 32, 512 / 32), 256, 0, stream>>>(W2, WT2, 512, 256);
    convT<<<dim3(512 / 32, 1024 / 32), 256, 0, stream>>>(W3, WT3, 1024, 512);
    convT<<<dim3(1024 / 32, 512 / 32), 256, 0, stream>>>(Wm1, WTm1, 512, 1024);
    convT<<<dim3(512 / 32, 1024 / 32), 256, 0, stream>>>(Wm2, WTm2, 1024, 512);

    // x -> bf16 into S1 block 0
    conv_x<<<(NN * 16 + 255) / 256, 256, 0, stream>>>(x, S1);

    // Layer 1
    prop_bf16<16><<<1250, 256, 0, stream>>>(rp, col, order, S1, 512, 0, 128);
    prop_bf16<16><<<1250, 256, 0, stream>>>(rp, col, order, S1, 512, 128, 256);
    prop_bf16<16><<<1250, 256, 0, stream>>>(rp, col, order, S1, 512, 256, 384);
    gemm_bf16<64, 0, 0><<<dim3(1, NNP / 64), 256, 0, stream>>>(S1, 512, WT1, 512, 128, b1, S2, 512, nullptr, nullptr);

    // Layer 2
    prop_bf16<16><<<1250, 256, 0, stream>>>(rp, col, order, S2, 512, 0, 128);
    prop_bf16<16><<<1250, 256, 0, stream>>>(rp, col, order, S2, 512, 128, 256);
    prop_bf16<16><<<1250, 256, 0, stream>>>(rp, col, order, S2, 512, 256, 384);
    gemm_bf16<64, 0, 0><<<dim3(2, NNP / 64), 256, 0, stream>>>(S2, 512, WT2, 512, 256, b2, S3, 1024, nullptr, nullptr);

    // Layer 3 (epilogue = bias + LDS-staged global max pool)
    prop_bf16<32><<<2500, 256, 0, stream>>>(rp, col, order, S3, 1024, 0, 256);
    prop_bf16<32><<<2500, 256, 0, stream>>>(rp, col, order, S3, 1024, 256, 512);
    prop_bf16<32><<<2500, 256, 0, stream>>>(rp, col, order, S3, 1024, 512, 768);
    hipMemsetAsync(genc, 0, (size_t)NG * 512 * 4, stream);
    gemm_bf16<128, 1, 0><<<dim3(4, NNP / 128), 256, 0, stream>>>(S3, 1024, WT3, 1024, 512, b3, nullptr, 0, genc, bat);

    // Head MLP (MFMA)
    g2bf<<<(NG * 512 + 255) / 256, 256, 0, stream>>>(genc, gb);
    gemm_bf16<64, 0, 1><<<dim3(8, 1), 256, 0, stream>>>(gb, 512, WTm1, 512, 1024, bm1, m1b, 1024, nullptr, nullptr);
    gemm_bf16<64, 0, 1><<<dim3(4, 1), 256, 0, stream>>>(m1b, 1024, WTm2, 1024, 512, bm2, m2b, 512, nullptr, nullptr);
    head3<<<NG, 256, 0, stream>>>(m2b, Wm3, bm3, out);
}

// Round 11
// 321.502 us; speedup vs baseline: 1.3532x; 1.3532x over previous
//
#include <hip/hip_runtime.h>
#include <stdint.h>

#define NN 20000
#define NNP 20096   // padded to multiple of 128 rows
#define NE 320000
#define NG 64

typedef unsigned short u16;
typedef __attribute__((ext_vector_type(8))) short short8;
typedef __attribute__((ext_vector_type(4))) float f32x4;

__device__ __forceinline__ void glds16(const void* g, const void* l) {
    __builtin_amdgcn_global_load_lds((const __attribute__((address_space(1))) void*)g,
                                     (__attribute__((address_space(3))) void*)l, 16, 0, 0);
}

__device__ __forceinline__ u16 f2bf(float f) {
    unsigned u = __float_as_uint(f);
    return (u16)((u + 0x7FFFu + ((u >> 16) & 1u)) >> 16);
}

// ---------------- CSR build ----------------
__global__ void hist_kernel(const int* __restrict__ dst, int* __restrict__ cnt, int E) {
    int i = blockIdx.x * blockDim.x + threadIdx.x;
    if (i < E) atomicAdd(&cnt[dst[i]], 1);
}

__global__ void scan_kernel(const int* __restrict__ cnt, int* __restrict__ rp, int n) {
    __shared__ int part[1024];
    int tid = threadIdx.x;
    const int CH = (n + 1023) / 1024;
    int base = tid * CH;
    int s = 0;
    for (int i = 0; i < CH; i++) { int idx = base + i; if (idx < n) s += cnt[idx]; }
    part[tid] = s;
    __syncthreads();
    for (int off = 1; off < 1024; off <<= 1) {
        int v = (tid >= off) ? part[tid - off] : 0;
        __syncthreads();
        part[tid] += v;
        __syncthreads();
    }
    int run = (tid == 0) ? 0 : part[tid - 1];
    for (int i = 0; i < CH; i++) {
        int idx = base + i;
        if (idx < n) { rp[idx] = run; run += cnt[idx]; }
    }
    if (tid == 1023) rp[n] = part[1023];
}

__global__ void copy_int(const int* __restrict__ a, int* __restrict__ b, int n) {
    int i = blockIdx.x * blockDim.x + threadIdx.x;
    if (i < n) b[i] = a[i];
}

__global__ void scatter_kernel(const int* __restrict__ src, const int* __restrict__ dstv,
                               int* __restrict__ ofs, int* __restrict__ col, int E) {
    int i = blockIdx.x * blockDim.x + threadIdx.x;
    if (i < E) {
        int p = atomicAdd(&ofs[dstv[i]], 1);
        col[p] = src[i];
    }
}

// ---------------- convert x -> bf16 into S1 block 0 ----------------
__global__ void conv_x(const float* __restrict__ x, u16* __restrict__ S1) {
    int i = blockIdx.x * blockDim.x + threadIdx.x;   // one per 8 elements
    if (i >= NN * 128 / 8) return;
    int row = i >> 4, c = (i & 15) * 8;
    const float* p = x + (size_t)row * 128 + c;
    uint4 r;
    unsigned* pr = (unsigned*)&r;
#pragma unroll
    for (int j = 0; j < 4; j++)
        pr[j] = (unsigned)f2bf(p[2 * j]) | ((unsigned)f2bf(p[2 * j + 1]) << 16);
    *(uint4*)(S1 + (size_t)row * 512 + c) = r;
}

// ---------------- LDS-tiled transpose+convert: WT[m][k] = bf16(W[k][m]), K,M mult of 32 ----------------
__global__ void convT(const float* __restrict__ W, u16* __restrict__ WT, int K, int M) {
    __shared__ float tile[32][33];
    int m0 = blockIdx.x * 32, k0 = blockIdx.y * 32;
    int tx = threadIdx.x & 31, ty = threadIdx.x >> 5;   // 256 threads: 8 rows/pass
#pragma unroll
    for (int i = 0; i < 32; i += 8)
        tile[ty + i][tx] = W[(size_t)(k0 + ty + i) * M + m0 + tx];
    __syncthreads();
#pragma unroll
    for (int i = 0; i < 32; i += 8)
        WT[(size_t)(m0 + ty + i) * K + k0 + tx] = f2bf(tile[tx][ty + i]);
}

// ---------------- decode pooled genc -> bf16 matrix ----------------
__global__ void g2bf(const unsigned* __restrict__ genc, u16* __restrict__ gb) {
    int i = blockIdx.x * blockDim.x + threadIdx.x;
    if (i >= NG * 512) return;
    unsigned u = genc[i];
    u = (u & 0x80000000u) ? (u ^ 0x80000000u) : ~u;
    gb[i] = f2bf(__uint_as_float(u));
}

// ---------------- propagation (bf16), unroll-4 ILP (best known: R8) ----------------
template <int NCHUNK>
__global__ __launch_bounds__(256) void prop_bf16(
    const int* __restrict__ rp, const int* __restrict__ col,
    u16* __restrict__ S, int stride, int in_off, int out_off) {
    constexpr int NPB = 256 / NCHUNK;
    int node = blockIdx.x * NPB + (threadIdx.x / NCHUNK);
    int c = threadIdx.x & (NCHUNK - 1);
    if (node >= NN) return;
    int s0 = rp[node], s1 = rp[node + 1];
    float acc[8] = {};
    const u16* base = S + in_off + c * 8;
    auto accum = [&](uint4 v) {
        const unsigned* pv = (const unsigned*)&v;
#pragma unroll
        for (int j = 0; j < 4; j++) {
            acc[2 * j]     += __uint_as_float(pv[j] << 16);
            acc[2 * j + 1] += __uint_as_float(pv[j] & 0xFFFF0000u);
        }
    };
    int e = s0;
    for (; e + 4 <= s1; e += 4) {
        int i0 = col[e], i1 = col[e + 1], i2 = col[e + 2], i3 = col[e + 3];
        uint4 v0 = *(const uint4*)(base + (size_t)i0 * stride);
        uint4 v1 = *(const uint4*)(base + (size_t)i1 * stride);
        uint4 v2 = *(const uint4*)(base + (size_t)i2 * stride);
        uint4 v3 = *(const uint4*)(base + (size_t)i3 * stride);
        accum(v0); accum(v1); accum(v2); accum(v3);
    }
    for (; e < s1; e++)
        accum(*(const uint4*)(base + (size_t)col[e] * stride));
    uint4 r;
    unsigned* pr = (unsigned*)&r;
#pragma unroll
    for (int j = 0; j < 4; j++)
        pr[j] = (unsigned)f2bf(acc[2 * j]) | ((unsigned)f2bf(acc[2 * j + 1]) << 16);
    *(uint4*)(S + (size_t)node * stride + out_off + c * 8) = r;
}

// ---------------- bf16 MFMA GEMM, TMx128 tile, BK=32, 4 waves ----------------
// Double-buffered stage-early K-loop; bijective XCD-chunked swizzle.
// A: [*][lda] bf16 row-major. BT: [M][Kp] bf16 row-major (pre-transposed W).
// EPI 0: out = bf16(act(acc+bias)), ACT 0=leaky 1=relu. EPI 1: LDS-staged max pool.
template <int TM, int EPI, int ACT>
__global__ __launch_bounds__(256) void gemm_bf16(
    const u16* __restrict__ A, int lda, const u16* __restrict__ BT,
    int Kp, int M, const float* __restrict__ bias,
    u16* __restrict__ outB, int ldo,
    unsigned* __restrict__ genc, const int* __restrict__ batch) {
    __shared__ u16 Al[2][TM * 32];
    __shared__ u16 Bl[2][128 * 32];
    __shared__ unsigned gbuf[EPI == 1 ? 256 : 4];
    constexpr int MR = TM / 32;   // m-fragments per wave
    int gx = gridDim.x;
    int total = gx * gridDim.y;
    int flat = blockIdx.x + gx * blockIdx.y;
    int q = total >> 3, r_ = total & 7;
    int k8 = flat & 7, i8 = flat >> 3;
    int v = (k8 < r_) ? (k8 * (q + 1) + i8) : (r_ * (q + 1) + (k8 - r_) * q + i8);
    int col0 = (v % gx) * 128, row0 = (v / gx) * TM;
    int t = threadIdx.x;
    int w = t >> 6, ln = t & 63;
    int wm = (w >> 1) * (TM / 2), wn = (w & 1) * 64;
    int srowB = w * 32 + (ln >> 2);
    int srowA = (TM == 128) ? srowB : (w * 16 + (ln >> 2));
    int skc = (ln & 3) * 8;
    f32x4 acc[MR][4] = {};

    if (EPI == 1) gbuf[t] = 0;     // published by first loop barrier

    auto stage = [&](int b, int k0) {
        if constexpr (TM == 128) {
            glds16(A + (size_t)(row0 + srowA) * lda + k0 + skc,      &Al[b][w * 1024]);
            glds16(A + (size_t)(row0 + srowA + 16) * lda + k0 + skc, &Al[b][w * 1024 + 512]);
        } else {
            glds16(A + (size_t)(row0 + srowA) * lda + k0 + skc,      &Al[b][w * 512]);
        }
        glds16(BT + (size_t)(col0 + srowB) * Kp + k0 + skc,          &Bl[b][w * 1024]);
        glds16(BT + (size_t)(col0 + srowB + 16) * Kp + k0 + skc,     &Bl[b][w * 1024 + 512]);
    };

    int nt = Kp / 32;
    stage(0, 0);
    for (int it = 0; it < nt; it++) {
        int cur = it & 1;
        __syncthreads();                 // implicit vmcnt(0): buf[cur] ready & visible
        if (it + 1 < nt) stage(cur ^ 1, (it + 1) * 32);   // async fill other buffer
        short8 af[MR], bf[4];
#pragma unroll
        for (int m = 0; m < MR; m++)
            af[m] = *(const short8*)&Al[cur][(wm + m * 16 + (ln & 15)) * 32 + (ln >> 4) * 8];
#pragma unroll
        for (int n = 0; n < 4; n++)
            bf[n] = *(const short8*)&Bl[cur][(wn + n * 16 + (ln & 15)) * 32 + (ln >> 4) * 8];
#pragma unroll
        for (int m = 0; m < MR; m++)
#pragma unroll
            for (int n = 0; n < 4; n++)
                acc[m][n] = __builtin_amdgcn_mfma_f32_16x16x32_bf16(af[m], bf[n], acc[m][n], 0, 0, 0);
    }

    int g_lo = (EPI == 1) ? batch[row0] : 0;
#pragma unroll
    for (int m = 0; m < MR; m++) {
#pragma unroll
        for (int r = 0; r < 4; r++) {
            int row = row0 + wm + m * 16 + (ln >> 4) * 4 + r;
            if (row < NN) {
                int gb_ = 0, gidx = 0;
                if (EPI == 1) { gb_ = batch[row]; gidx = gb_ - g_lo; }
#pragma unroll
                for (int n = 0; n < 4; n++) {
                    int cl = wn + n * 16 + (ln & 15);
                    float vv = acc[m][n][r] + bias[col0 + cl];
                    if (EPI == 0) {
                        vv = ACT ? fmaxf(vv, 0.f) : (vv > 0.f ? vv : 0.01f * vv);
                        outB[(size_t)row * ldo + col0 + cl] = f2bf(vv);
                    } else {
                        unsigned u = __float_as_uint(vv);
                        u = (u & 0x80000000u) ? ~u : (u | 0x80000000u);
                        if (gidx < 2) atomicMax(&gbuf[gidx * 128 + cl], u);
                        else          atomicMax(&genc[(size_t)gb_ * M + col0 + cl], u);
                    }
                }
            }
        }
    }
    if (EPI == 1) {
        __syncthreads();
        int j = t >> 7, c = t & 127;
        unsigned u = gbuf[j * 128 + c];
        if (u && g_lo + j < NG) atomicMax(&genc[(size_t)(g_lo + j) * M + col0 + c], u);
    }
}

// ---------------- final head layer: out[r][m] = dot(m2b[r], Wm3[:,m]) + b[m] ----------------
__global__ void head3(const u16* __restrict__ m2b, const float* __restrict__ W,
                      const float* __restrict__ b, float* __restrict__ outp) {
    int r = blockIdx.x;           // 64 blocks
    int w = threadIdx.x >> 6;     // wave = output column (4)
    int ln = threadIdx.x & 63;
    float acc = 0.f;
    for (int k = ln; k < 512; k += 64) {
        float v = __uint_as_float(((unsigned)m2b[r * 512 + k]) << 16);
        acc += v * W[k * 4 + w];
    }
#pragma unroll
    for (int o = 32; o; o >>= 1) acc += __shfl_down(acc, o, 64);
    if (ln == 0) outp[r * 4 + w] = acc + b[w];
}

extern "C" void kernel_launch(void* const* d_in, const int* in_sizes, int n_in,
                              void* d_out, int out_size, void* d_ws, size_t ws_size,
                              hipStream_t stream) {
    const float* x   = (const float*)d_in[0];
    const int*   ei  = (const int*)d_in[1];
    const int*   bat = (const int*)d_in[2];
    const float* W1  = (const float*)d_in[3];
    const float* b1  = (const float*)d_in[4];
    const float* W2  = (const float*)d_in[5];
    const float* b2  = (const float*)d_in[6];
    const float* W3  = (const float*)d_in[7];
    const float* b3  = (const float*)d_in[8];
    const float* Wm1 = (const float*)d_in[9];
    const float* bm1 = (const float*)d_in[10];
    const float* Wm2 = (const float*)d_in[11];
    const float* bm2 = (const float*)d_in[12];
    const float* Wm3 = (const float*)d_in[13];
    const float* bm3 = (const float*)d_in[14];
    float* out = (float*)d_out;

    char* ws = (char*)d_ws;
    size_t off = 0;
    auto alloc = [&](size_t bytes) -> void* {
        void* p = ws + off;
        off += (bytes + 255) & ~(size_t)255;
        return p;
    };
    int*      cnt  = (int*)alloc((size_t)NN * 4);
    int*      rp   = (int*)alloc((size_t)(NN + 1) * 4);
    int*      col  = (int*)alloc((size_t)NE * 4);
    u16*      S1   = (u16*)alloc((size_t)NNP * 512 * 2);   // [x|Ax|A2x|A3x]
    u16*      S2   = (u16*)alloc((size_t)NNP * 512 * 2);   // [h1|Ah1|A2h1|A3h1]
    u16*      S3   = (u16*)alloc((size_t)NNP * 1024 * 2);  // [h2|Ah2|A2h2|A3h2]
    u16*      WT1  = (u16*)alloc((size_t)128 * 512 * 2);
    u16*      WT2  = (u16*)alloc((size_t)256 * 512 * 2);
    u16*      WT3  = (u16*)alloc((size_t)512 * 1024 * 2);
    u16*      WTm1 = (u16*)alloc((size_t)1024 * 512 * 2);
    u16*      WTm2 = (u16*)alloc((size_t)512 * 1024 * 2);
    unsigned* genc = (unsigned*)alloc((size_t)NG * 512 * 4);
    u16*      gb   = (u16*)alloc((size_t)NG * 512 * 2);
    u16*      m1b  = (u16*)alloc((size_t)NG * 1024 * 2);
    u16*      m2b  = (u16*)alloc((size_t)NG * 512 * 2);

    const int* src  = ei;
    const int* dstv = ei + NE;

    // CSR by destination
    hipMemsetAsync(cnt, 0, (size_t)NN * 4, stream);
    hist_kernel<<<(NE + 255) / 256, 256, 0, stream>>>(dstv, cnt, NE);
    scan_kernel<<<1, 1024, 0, stream>>>(cnt, rp, NN);
    copy_int<<<(NN + 255) / 256, 256, 0, stream>>>(rp, cnt, NN);
    scatter_kernel<<<(NE + 255) / 256, 256, 0, stream>>>(src, dstv, cnt, col, NE);

    // weights -> bf16, transposed [M][K] (K,M all multiples of 32)
    convT<<<dim3(128 / 32, 512 / 32), 256, 0, stream>>>(W1, WT1, 512, 128);
    convT<<<dim3(256 / 32, 512 / 32), 256, 0, stream>>>(W2, WT2, 512, 256);
    convT<<<dim3(512 / 32, 1024 / 32), 256, 0, stream>>>(W3, WT3, 1024, 512);
    convT<<<dim3(1024 / 32, 512 / 32), 256, 0, stream>>>(Wm1, WTm1, 512, 1024);
    convT<<<dim3(512 / 32, 1024 / 32), 256, 0, stream>>>(Wm2, WTm2, 1024, 512);

    // x -> bf16 into S1 block 0
    conv_x<<<(NN * 16 + 255) / 256, 256, 0, stream>>>(x, S1);

    // Layer 1
    prop_bf16<16><<<1250, 256, 0, stream>>>(rp, col, S1, 512, 0, 128);
    prop_bf16<16><<<1250, 256, 0, stream>>>(rp, col, S1, 512, 128, 256);
    prop_bf16<16><<<1250, 256, 0, stream>>>(rp, col, S1, 512, 256, 384);
    gemm_bf16<64, 0, 0><<<dim3(1, NNP / 64), 256, 0, stream>>>(S1, 512, WT1, 512, 128, b1, S2, 512, nullptr, nullptr);

    // Layer 2
    prop_bf16<16><<<1250, 256, 0, stream>>>(rp, col, S2, 512, 0, 128);
    prop_bf16<16><<<1250, 256, 0, stream>>>(rp, col, S2, 512, 128, 256);
    prop_bf16<16><<<1250, 256, 0, stream>>>(rp, col, S2, 512, 256, 384);
    gemm_bf16<64, 0, 0><<<dim3(2, NNP / 64), 256, 0, stream>>>(S2, 512, WT2, 512, 256, b2, S3, 1024, nullptr, nullptr);

    // Layer 3 (TM=64: 1256 blocks -> ~5/CU occupancy; epilogue = bias + LDS-staged max pool)
    prop_bf16<32><<<2500, 256, 0, stream>>>(rp, col, S3, 1024, 0, 256);
    prop_bf16<32><<<2500, 256, 0, stream>>>(rp, col, S3, 1024, 256, 512);
    prop_bf16<32><<<2500, 256, 0, stream>>>(rp, col, S3, 1024, 512, 768);
    hipMemsetAsync(genc, 0, (size_t)NG * 512 * 4, stream);
    gemm_bf16<64, 1, 0><<<dim3(4, NNP / 64), 256, 0, stream>>>(S3, 1024, WT3, 1024, 512, b3, nullptr, 0, genc, bat);

    // Head MLP (MFMA)
    g2bf<<<(NG * 512 + 255) / 256, 256, 0, stream>>>(genc, gb);
    gemm_bf16<64, 0, 1><<<dim3(8, 1), 256, 0, stream>>>(gb, 512, WTm1, 512, 1024, bm1, m1b, 1024, nullptr, nullptr);
    gemm_bf16<64, 0, 1><<<dim3(4, 1), 256, 0, stream>>>(m1b, 1024, WTm2, 1024, 512, bm2, m2b, 512, nullptr, nullptr);
    head3<<<NG, 256, 0, stream>>>(m2b, Wm3, bm3, out);
}